// Round 4
// baseline (502.811 us; speedup 1.0000x reference)
//
#include <hip/hip_runtime.h>
#include <hip/hip_cooperative_groups.h>

namespace cg = cooperative_groups;

// ConvLSTM2D MI355X, R4: ONE persistent cooperative kernel for all 10 steps.
// B=8,T=10,H=W=64,CIN=32,F=64,4F=256,G=4.
// Grid 256 blocks x 512 thr (8 waves). Block owns (b, 16x8 px tile) across all
// steps; c-state in REGISTERS; h exchanged via bf16 double-buffered ring in ws
// (halo crosses block boundaries); grid.sync() between steps (release/acquire
// fences handle cross-XCD L2 visibility). Per step: stage X halo (f32->bf16)
// + H halo (bf16) into LDS, one block barrier, 9+18 MFMA chunks (K=864),
// in-register gates, write out f32 + h ring bf16.

typedef __attribute__((ext_vector_type(8))) short short8v;
typedef __attribute__((ext_vector_type(4))) float f32x4;
typedef unsigned short u16;

__device__ __forceinline__ u16 f2bf(float x) {
    union { float f; unsigned u; } a; a.f = x;
    unsigned r = a.u + 0x7FFFu + ((a.u >> 16) & 1u);   // RNE
    return (u16)(r >> 16);
}
__device__ __forceinline__ float sigf(float x) { return 1.0f / (1.0f + __expf(-x)); }
__device__ __forceinline__ float tanhf_(float x) {
    float e = __expf(2.0f * x);
    return 1.0f - 2.0f / (e + 1.0f);
}

// ---- prep: weights -> MFMA-native bf16  Wt[chunk][kb][co][i] ----
__global__ __launch_bounds__(256)
void prep_w(const float* __restrict__ kern, const float* __restrict__ rk,
            u16* __restrict__ wt_in, u16* __restrict__ wt_rk) {
    int idx = blockIdx.x * 256 + threadIdx.x;
    if (idx >= 82944) return;
    const float* s;
    u16* dst;
    if (idx < 9216) {
        int co = idx & 255, ckb = idx >> 8;          // 0..35 = tap*4+kb
        int tap = ckb >> 2, kb = ckb & 3;
        s = kern + (size_t)((tap << 5) + (kb << 3)) * 256 + co;
        dst = wt_in + (size_t)idx * 8;
    } else {
        int j = idx - 9216;
        int co = j & 255, rest = j >> 8;             // 0..287
        int kb = rest & 3, gc = rest >> 2;           // gc = g*18 + c
        int g = gc / 18, cc = gc - g * 18;
        int tap = cc >> 1;
        int cib = ((cc & 1) << 5) + (kb << 3);
        s = rk + (size_t)(((g * 9 + tap) << 6) + cib) * 256 + co;
        dst = wt_rk + (size_t)j * 8;
    }
    union { u16 u[8]; uint4 q; } o;
    #pragma unroll
    for (int i = 0; i < 8; ++i) o.u[i] = f2bf(s[i * 256]);
    *(uint4*)dst = o.q;
}

// ---- persistent fused conv + gates, all timesteps ----
__global__ __launch_bounds__(512, 2)
void lstm_all(const float* __restrict__ xf,   // (8,10,64,64,32) f32
              const u16* __restrict__ wt_in, const u16* __restrict__ wt_rk,
              const float* __restrict__ bias, const int* __restrict__ labels,
              u16* __restrict__ hb0, u16* __restrict__ hb1,  // bf16 h ring
              float* __restrict__ out)        // (8,10,4096,64) f32
{
    // X halo: [kb 4][180 pos][8 ci] @0 ; H halo: [kb 8][180 pos][8 ci] @5760
    __shared__ short hal[17280];   // 34,560 B
    cg::grid_group grid = cg::this_grid();

    const int tid  = threadIdx.x;
    const int lane = tid & 63;
    const int w    = tid >> 6;
    const int pxh  = w >> 2;                   // pixel half (rows 0-7 / 8-15)
    const int wq   = w & 3;                    // f-slice of 16
    const int b    = blockIdx.x >> 5;
    const int tile = blockIdx.x & 31;
    const int y0 = (tile >> 3) << 4;           // 4 y-tiles of 16 rows
    const int x0 = (tile & 7) << 3;            // 8 x-tiles of 8 cols
    const int g = labels[b];

    const int co_l = lane & 15;
    const int kbl  = lane >> 4;
    const int prow = (lane & 15) >> 3, pcol = lane & 7;

    // bias per gate (fixed channel f = wq*16+co_l)
    float bv[4];
    #pragma unroll
    for (int n = 0; n < 4; ++n)
        bv[n] = bias[(g << 8) + (n << 6) + (wq << 4) + co_l];

    int aoffm[4];
    #pragma unroll
    for (int m = 0; m < 4; ++m)
        aoffm[m] = ((pxh << 3) + (m << 1) + prow) * 10 + pcol;

    // precomputed output offsets for the 16 pixels this thread owns
    const int f = (wq << 4) + co_l;
    int poff[4][4];
    #pragma unroll
    for (int m = 0; m < 4; ++m)
        #pragma unroll
        for (int rr = 0; rr < 4; ++rr) {
            int pf = (kbl << 2) + rr;
            int yy = y0 + (pxh << 3) + (m << 1) + (pf >> 3);
            int xx = x0 + (pf & 7);
            poff[m][rr] = (((yy << 6) + xx) << 6) + f;
        }

    // c-state in registers
    float cst[4][4];
    #pragma unroll
    for (int m = 0; m < 4; ++m)
        #pragma unroll
        for (int rr = 0; rr < 4; ++rr) cst[m][rr] = 0.0f;

    const float* xsrc = xf + ((size_t)b * 10 << 17);
    float* ob0 = out + ((size_t)b * 10 << 18);

    for (int t = 0; t < 10; ++t) {
        const u16* hrd = ((t & 1) ? hb0 : hb1) + ((size_t)b << 18);
        u16*       hwr = ((t & 1) ? hb1 : hb0) + ((size_t)b << 18);

        // ---- stage X halo (f32 -> bf16), 720 slots ----
        {
            const float* src = xsrc + ((size_t)t << 17);
            #pragma unroll 2
            for (int s = tid; s < 720; s += 512) {
                int pos = s >> 2, kb = s & 3;
                int hy = pos / 10, hx = pos - hy * 10;
                int gy = y0 + hy - 1, gx = x0 + hx - 1;
                union { u16 u[8]; short8v v; } o;
                o.v = (short8v){0,0,0,0,0,0,0,0};
                if ((unsigned)gy < 64u && (unsigned)gx < 64u) {
                    const float* p = src + (((gy << 6) + gx) << 5) + (kb << 3);
                    float4 a0 = *(const float4*)p;
                    float4 a1 = *(const float4*)(p + 4);
                    o.u[0] = f2bf(a0.x); o.u[1] = f2bf(a0.y);
                    o.u[2] = f2bf(a0.z); o.u[3] = f2bf(a0.w);
                    o.u[4] = f2bf(a1.x); o.u[5] = f2bf(a1.y);
                    o.u[6] = f2bf(a1.z); o.u[7] = f2bf(a1.w);
                }
                *(short8v*)&hal[kb * 1440 + pos * 8] = o.v;
            }
        }
        // ---- stage H halo (bf16), 1440 slots ----
        if (t > 0) {
            #pragma unroll 3
            for (int s = tid; s < 1440; s += 512) {
                int pos = s >> 3, kb = s & 7;
                int hy = pos / 10, hx = pos - hy * 10;
                int gy = y0 + hy - 1, gx = x0 + hx - 1;
                short8v v = (short8v){0,0,0,0,0,0,0,0};
                if ((unsigned)gy < 64u && (unsigned)gx < 64u)
                    v = *(const short8v*)&hrd[(((gy << 6) + gx) << 6) + (kb << 3)];
                *(short8v*)&hal[5760 + kb * 1440 + pos * 8] = v;
            }
        }
        __syncthreads();

        // acc[m][n]: m = px frag (16 px = 2 rows x 8 cols), n = gate
        f32x4 acc[4][4];
        #pragma unroll
        for (int n = 0; n < 4; ++n)
            #pragma unroll
            for (int m = 0; m < 4; ++m)
                acc[m][n] = (f32x4){bv[n], bv[n], bv[n], bv[n]};

        // ---- phase X: 9 chunks ----
        #pragma unroll 3
        for (int tap = 0; tap < 9; ++tap) {
            const int koff = (tap / 3) * 10 + (tap % 3);
            const u16* wb = wt_in + (size_t)((((tap << 2) + kbl) << 8) + (wq << 4) + co_l) * 8;
            short8v bfr[4], af[4];
            #pragma unroll
            for (int n = 0; n < 4; ++n)
                bfr[n] = *(const short8v*)&wb[(size_t)n << 9];
            #pragma unroll
            for (int m = 0; m < 4; ++m)
                af[m] = *(const short8v*)&hal[kbl * 1440 + (aoffm[m] + koff) * 8];
            #pragma unroll
            for (int m = 0; m < 4; ++m)
                #pragma unroll
                for (int n = 0; n < 4; ++n)
                    acc[m][n] = __builtin_amdgcn_mfma_f32_16x16x32_bf16(af[m], bfr[n], acc[m][n], 0, 0, 0);
        }

        // ---- phase H: 18 chunks ----
        if (t > 0) {
            #pragma unroll 3
            for (int c = 0; c < 18; ++c) {
                const int tap = c >> 1;
                const int koff = (tap / 3) * 10 + (tap % 3);
                const u16* wb = wt_rk + (size_t)(((((g * 18 + c) << 2) + kbl) << 8) + (wq << 4) + co_l) * 8;
                short8v bfr[4], af[4];
                #pragma unroll
                for (int n = 0; n < 4; ++n)
                    bfr[n] = *(const short8v*)&wb[(size_t)n << 9];
                const int abase = 5760 + (((c & 1) << 2) + kbl) * 1440;
                #pragma unroll
                for (int m = 0; m < 4; ++m)
                    af[m] = *(const short8v*)&hal[abase + (aoffm[m] + koff) * 8];
                #pragma unroll
                for (int m = 0; m < 4; ++m)
                    #pragma unroll
                    for (int n = 0; n < 4; ++n)
                        acc[m][n] = __builtin_amdgcn_mfma_f32_16x16x32_bf16(af[m], bfr[n], acc[m][n], 0, 0, 0);
            }
        }

        // ---- gates in-register + writeback ----
        float* ob = ob0 + ((size_t)t << 18);
        #pragma unroll
        for (int m = 0; m < 4; ++m) {
            #pragma unroll
            for (int rr = 0; rr < 4; ++rr) {
                int off = poff[m][rr];
                float zi = acc[m][0][rr], zf = acc[m][1][rr];
                float zg = acc[m][2][rr], zo = acc[m][3][rr];
                float cn = sigf(zf) * cst[m][rr] + sigf(zi) * tanhf_(zg);
                float hn = sigf(zo) * tanhf_(cn);
                cst[m][rr] = cn;
                ob[off]  = hn;
                hwr[off] = f2bf(hn);
            }
        }

        grid.sync();   // h ring visible to all blocks before next step
    }
}

extern "C" void kernel_launch(void* const* d_in, const int* in_sizes, int n_in,
                              void* d_out, int out_size, void* d_ws, size_t ws_size,
                              hipStream_t stream)
{
    const float* x    = (const float*)d_in[0];
    const int*   lbl  = (const int*)  d_in[1];
    const float* kern = (const float*)d_in[2];
    const float* rk   = (const float*)d_in[3];
    const float* bias = (const float*)d_in[4];
    float* out = (float*)d_out;

    // ws: hb0 | hb1 (bf16 h ring) | wt_in | wt_rk   ~9.7 MB
    u16* hb0   = (u16*)d_ws;
    u16* hb1   = hb0 + 2097152;
    u16* wt_in = hb1 + 2097152;
    u16* wt_rk = wt_in + 73728;

    hipLaunchKernelGGL(prep_w, dim3(324), dim3(256), 0, stream, kern, rk, wt_in, wt_rk);

    void* args[] = { (void*)&x, (void*)&wt_in, (void*)&wt_rk, (void*)&bias,
                     (void*)&lbl, (void*)&hb0, (void*)&hb1, (void*)&out };
    hipLaunchCooperativeKernel((const void*)lstm_all, dim3(256), dim3(512),
                               args, 0, stream);
}

// Round 5
// 448.640 us; speedup vs baseline: 1.1207x; 1.1207x over previous
//
#include <hip/hip_runtime.h>

// ConvLSTM2D MI355X, R5: persistent kernel (all 10 steps, 1 dispatch) with a
// hand-rolled grid barrier (cg::grid.sync measured ~35us/step in R4 -> replace).
// B=8,T=10,H=W=64,CIN=32,F=64,4F=256,G=4.
// Grid 256 blocks x 512 thr (8 waves), cooperative launch (co-residency
// guarantee only; no cg::sync). Block owns (b, 16x8 tile); c in registers;
// h ring bf16 double-buffered in ws. Barrier: per-step fresh counter, per-wave
// vmcnt drain + thread0 agent-release fence + fetch_add; X(t+1) staged between
// arrive and spin (h-independent -> hides barrier latency); thread0 bounded
// relaxed-agent spin; syncthreads + all-wave agent-acquire fence before
// reading neighbor h.

typedef __attribute__((ext_vector_type(8))) short short8v;
typedef __attribute__((ext_vector_type(4))) float f32x4;
typedef unsigned short u16;

__device__ __forceinline__ u16 f2bf(float x) {
    union { float f; unsigned u; } a; a.f = x;
    unsigned r = a.u + 0x7FFFu + ((a.u >> 16) & 1u);   // RNE
    return (u16)(r >> 16);
}
__device__ __forceinline__ float sigf(float x) { return 1.0f / (1.0f + __expf(-x)); }
__device__ __forceinline__ float tanhf_(float x) {
    float e = __expf(2.0f * x);
    return 1.0f - 2.0f / (e + 1.0f);
}

// ---- prep: weights -> MFMA-native bf16 + zero barrier counters ----
__global__ __launch_bounds__(256)
void prep_w(const float* __restrict__ kern, const float* __restrict__ rk,
            u16* __restrict__ wt_in, u16* __restrict__ wt_rk,
            unsigned* __restrict__ cnt) {
    int idx = blockIdx.x * 256 + threadIdx.x;
    if (blockIdx.x == 0 && threadIdx.x < 16) cnt[threadIdx.x] = 0u;
    if (idx >= 82944) return;
    const float* s;
    u16* dst;
    if (idx < 9216) {
        int co = idx & 255, ckb = idx >> 8;          // 0..35 = tap*4+kb
        int tap = ckb >> 2, kb = ckb & 3;
        s = kern + (size_t)((tap << 5) + (kb << 3)) * 256 + co;
        dst = wt_in + (size_t)idx * 8;
    } else {
        int j = idx - 9216;
        int co = j & 255, rest = j >> 8;             // 0..287
        int kb = rest & 3, gc = rest >> 2;           // gc = g*18 + c
        int g = gc / 18, cc = gc - g * 18;
        int tap = cc >> 1;
        int cib = ((cc & 1) << 5) + (kb << 3);
        s = rk + (size_t)(((g * 9 + tap) << 6) + cib) * 256 + co;
        dst = wt_rk + (size_t)j * 8;
    }
    union { u16 u[8]; uint4 q; } o;
    #pragma unroll
    for (int i = 0; i < 8; ++i) o.u[i] = f2bf(s[i * 256]);
    *(uint4*)dst = o.q;
}

__device__ __forceinline__ void stageX(const float* __restrict__ src,
                                       short* __restrict__ halX,
                                       int tid, int y0, int x0) {
    #pragma unroll 2
    for (int s = tid; s < 720; s += 512) {
        int pos = s >> 2, kb = s & 3;
        int hy = pos / 10, hx = pos - hy * 10;
        int gy = y0 + hy - 1, gx = x0 + hx - 1;
        union { u16 u[8]; short8v v; } o;
        o.v = (short8v){0,0,0,0,0,0,0,0};
        if ((unsigned)gy < 64u && (unsigned)gx < 64u) {
            const float* p = src + (((gy << 6) + gx) << 5) + (kb << 3);
            float4 a0 = *(const float4*)p;
            float4 a1 = *(const float4*)(p + 4);
            o.u[0] = f2bf(a0.x); o.u[1] = f2bf(a0.y);
            o.u[2] = f2bf(a0.z); o.u[3] = f2bf(a0.w);
            o.u[4] = f2bf(a1.x); o.u[5] = f2bf(a1.y);
            o.u[6] = f2bf(a1.z); o.u[7] = f2bf(a1.w);
        }
        *(short8v*)&halX[kb * 1440 + pos * 8] = o.v;
    }
}

// ---- persistent fused conv + gates, all timesteps ----
__global__ __launch_bounds__(512, 2)
void lstm_all(const float* __restrict__ xf,   // (8,10,64,64,32) f32
              const u16* __restrict__ wt_in, const u16* __restrict__ wt_rk,
              const float* __restrict__ bias, const int* __restrict__ labels,
              u16* __restrict__ hb0, u16* __restrict__ hb1,  // bf16 h ring
              float* __restrict__ out,        // (8,10,4096,64) f32
              unsigned* __restrict__ cnt)     // 10 barrier counters (zeroed)
{
    // X halo: [kb 4][180 pos][8 ci] @0 ; H halo: [kb 8][180 pos][8 ci] @5760
    __shared__ short hal[17280];   // 34,560 B

    const int tid  = threadIdx.x;
    const int lane = tid & 63;
    const int w    = tid >> 6;
    const int pxh  = w >> 2;                   // pixel half (rows 0-7 / 8-15)
    const int wq   = w & 3;                    // f-slice of 16
    const int b    = blockIdx.x >> 5;
    const int tile = blockIdx.x & 31;
    const int y0 = (tile >> 3) << 4;
    const int x0 = (tile & 7) << 3;
    const int g = labels[b];

    const int co_l = lane & 15;
    const int kbl  = lane >> 4;
    const int prow = (lane & 15) >> 3, pcol = lane & 7;

    float bv[4];
    #pragma unroll
    for (int n = 0; n < 4; ++n)
        bv[n] = bias[(g << 8) + (n << 6) + (wq << 4) + co_l];

    int aoffm[4];
    #pragma unroll
    for (int m = 0; m < 4; ++m)
        aoffm[m] = ((pxh << 3) + (m << 1) + prow) * 10 + pcol;

    const int f = (wq << 4) + co_l;
    int poff[4][4];
    #pragma unroll
    for (int m = 0; m < 4; ++m)
        #pragma unroll
        for (int rr = 0; rr < 4; ++rr) {
            int pf = (kbl << 2) + rr;
            int yy = y0 + (pxh << 3) + (m << 1) + (pf >> 3);
            int xx = x0 + (pf & 7);
            poff[m][rr] = (((yy << 6) + xx) << 6) + f;
        }

    float cst[4][4];
    #pragma unroll
    for (int m = 0; m < 4; ++m)
        #pragma unroll
        for (int rr = 0; rr < 4; ++rr) cst[m][rr] = 0.0f;

    const float* xsrc = xf + ((size_t)b * 10 << 17);
    float* ob0 = out + ((size_t)b * 10 << 18);

    // prologue: stage X(0)
    stageX(xsrc, hal, tid, y0, x0);
    __syncthreads();

    for (int t = 0; t < 10; ++t) {
        u16* hwr = ((t & 1) ? hb1 : hb0) + ((size_t)b << 18);

        f32x4 acc[4][4];
        #pragma unroll
        for (int n = 0; n < 4; ++n)
            #pragma unroll
            for (int m = 0; m < 4; ++m)
                acc[m][n] = (f32x4){bv[n], bv[n], bv[n], bv[n]};

        // ---- phase X: 9 chunks ----
        #pragma unroll 3
        for (int tap = 0; tap < 9; ++tap) {
            const int koff = (tap / 3) * 10 + (tap % 3);
            const u16* wb = wt_in + (size_t)((((tap << 2) + kbl) << 8) + (wq << 4) + co_l) * 8;
            short8v bfr[4], af[4];
            #pragma unroll
            for (int n = 0; n < 4; ++n)
                bfr[n] = *(const short8v*)&wb[(size_t)n << 9];
            #pragma unroll
            for (int m = 0; m < 4; ++m)
                af[m] = *(const short8v*)&hal[kbl * 1440 + (aoffm[m] + koff) * 8];
            #pragma unroll
            for (int m = 0; m < 4; ++m)
                #pragma unroll
                for (int n = 0; n < 4; ++n)
                    acc[m][n] = __builtin_amdgcn_mfma_f32_16x16x32_bf16(af[m], bfr[n], acc[m][n], 0, 0, 0);
        }

        // ---- phase H: 18 chunks ----
        if (t > 0) {
            #pragma unroll 3
            for (int c = 0; c < 18; ++c) {
                const int tap = c >> 1;
                const int koff = (tap / 3) * 10 + (tap % 3);
                const u16* wb = wt_rk + (size_t)(((((g * 18 + c) << 2) + kbl) << 8) + (wq << 4) + co_l) * 8;
                short8v bfr[4], af[4];
                #pragma unroll
                for (int n = 0; n < 4; ++n)
                    bfr[n] = *(const short8v*)&wb[(size_t)n << 9];
                const int abase = 5760 + (((c & 1) << 2) + kbl) * 1440;
                #pragma unroll
                for (int m = 0; m < 4; ++m)
                    af[m] = *(const short8v*)&hal[abase + (aoffm[m] + koff) * 8];
                #pragma unroll
                for (int m = 0; m < 4; ++m)
                    #pragma unroll
                    for (int n = 0; n < 4; ++n)
                        acc[m][n] = __builtin_amdgcn_mfma_f32_16x16x32_bf16(af[m], bfr[n], acc[m][n], 0, 0, 0);
            }
        }

        // ---- gates in-register + writeback ----
        float* ob = ob0 + ((size_t)t << 18);
        #pragma unroll
        for (int m = 0; m < 4; ++m) {
            #pragma unroll
            for (int rr = 0; rr < 4; ++rr) {
                int off = poff[m][rr];
                float zi = acc[m][0][rr], zf = acc[m][1][rr];
                float zg = acc[m][2][rr], zo = acc[m][3][rr];
                float cn = sigf(zf) * cst[m][rr] + sigf(zi) * tanhf_(zg);
                float hn = sigf(zo) * tanhf_(cn);
                cst[m][rr] = cn;
                ob[off]  = hn;
                hwr[off] = f2bf(hn);
            }
        }

        if (t < 9) {
            // ---- hand-rolled grid barrier (fresh counter per step) ----
            asm volatile("s_waitcnt vmcnt(0)" ::: "memory");  // this wave's h stores in L2
            __syncthreads();                                   // all waves drained
            if (tid == 0) {
                __builtin_amdgcn_fence(__ATOMIC_RELEASE, "agent");  // L2 writeback
                __hip_atomic_fetch_add(&cnt[t], 1u, __ATOMIC_RELAXED,
                                       __HIP_MEMORY_SCOPE_AGENT);
            }
            // stage X(t+1) while other blocks arrive (h-independent)
            stageX(xsrc + ((size_t)(t + 1) << 17), hal, tid, y0, x0);
            if (tid == 0) {
                int guard = 0;
                while (__hip_atomic_load(&cnt[t], __ATOMIC_RELAXED,
                                         __HIP_MEMORY_SCOPE_AGENT) < 256u
                       && guard < (1 << 22)) {
                    __builtin_amdgcn_s_sleep(1);
                    ++guard;
                }
            }
            __syncthreads();
            __builtin_amdgcn_fence(__ATOMIC_ACQUIRE, "agent");  // inv caches

            // ---- stage H(t+1) from h written this step ----
            #pragma unroll 3
            for (int s = tid; s < 1440; s += 512) {
                int pos = s >> 3, kb = s & 7;
                int hy = pos / 10, hx = pos - hy * 10;
                int gy = y0 + hy - 1, gx = x0 + hx - 1;
                short8v v = (short8v){0,0,0,0,0,0,0,0};
                if ((unsigned)gy < 64u && (unsigned)gx < 64u) {
                    const u16* hsrc = ((t & 1) ? hb1 : hb0) + ((size_t)b << 18);
                    v = *(const short8v*)&hsrc[(((gy << 6) + gx) << 6) + (kb << 3)];
                }
                *(short8v*)&hal[5760 + kb * 1440 + pos * 8] = v;
            }
            __syncthreads();
        }
    }
}

extern "C" void kernel_launch(void* const* d_in, const int* in_sizes, int n_in,
                              void* d_out, int out_size, void* d_ws, size_t ws_size,
                              hipStream_t stream)
{
    const float* x    = (const float*)d_in[0];
    const int*   lbl  = (const int*)  d_in[1];
    const float* kern = (const float*)d_in[2];
    const float* rk   = (const float*)d_in[3];
    const float* bias = (const float*)d_in[4];
    float* out = (float*)d_out;

    // ws: hb0 | hb1 (bf16 h ring) | wt_in | wt_rk | counters  ~9.7 MB
    u16* hb0   = (u16*)d_ws;
    u16* hb1   = hb0 + 2097152;
    u16* wt_in = hb1 + 2097152;
    u16* wt_rk = wt_in + 73728;
    unsigned* cnt = (unsigned*)(wt_rk + 589824);

    hipLaunchKernelGGL(prep_w, dim3(324), dim3(256), 0, stream,
                       kern, rk, wt_in, wt_rk, cnt);

    void* args[] = { (void*)&x, (void*)&wt_in, (void*)&wt_rk, (void*)&bias,
                     (void*)&lbl, (void*)&hb0, (void*)&hb1, (void*)&out,
                     (void*)&cnt };
    hipLaunchCooperativeKernel((const void*)lstm_all, dim3(256), dim3(512),
                               args, 0, stream);
}

// Round 7
// 245.863 us; speedup vs baseline: 2.0451x; 1.8248x over previous
//
#include <hip/hip_runtime.h>

// ConvLSTM2D MI355X, R7: R6 structure with the double-buffer WAR race fixed by
// a TRIPLE-buffered weight slab (write->read distance 2 barrier intervals) +
// sched_barrier(0) pinning around raw s_barrier.
// B=8,T=10,H=W=64,CIN=32,F=64,4F=256,G=4.
// Step kernel: grid 512 = [b 8][tile 32][fh 2], 512 thr = 8 waves.
// Block = 128 px (16x8) x 128 co (4 gates x 32 f). Wave: 32 px x 64 co.
// 2 blocks/CU -> 4 waves/SIMD. Weights: per-chunk 8KB slab staged to LDS via
// global_load_lds(16B), 3-buffer rotation, counted vmcnt(1) + raw s_barrier
// (next-chunk stage stays in flight across the barrier; never drains to 0 in
// the loop). Halo (X bf16 + H bf16) in LDS. Gates in-register; c f32
// prefetched at kernel top; h bf16 double-buffered ring.

typedef __attribute__((ext_vector_type(8))) short short8v;
typedef __attribute__((ext_vector_type(4))) float f32x4;
typedef unsigned short u16;
typedef unsigned int u32;

__device__ __forceinline__ u16 f2bf(float x) {
    union { float f; unsigned u; } a; a.f = x;
    unsigned r = a.u + 0x7FFFu + ((a.u >> 16) & 1u);   // RNE
    return (u16)(r >> 16);
}
__device__ __forceinline__ float sigf(float x) { return 1.0f / (1.0f + __expf(-x)); }
__device__ __forceinline__ float tanhf_(float x) {
    float e = __expf(2.0f * x);
    return 1.0f - 2.0f / (e + 1.0f);
}

// ---- prep: x f32 -> bf16 ----
__global__ __launch_bounds__(256)
void prep_x(const float* __restrict__ x, u16* __restrict__ xb) {
    size_t i = (size_t)blockIdx.x * 256 + threadIdx.x;
    for (; i < 2621440u; i += (size_t)2048 * 256) {
        float4 v = ((const float4*)x)[i];
        union { u16 u[4]; uint2 q; } o;
        o.u[0] = f2bf(v.x); o.u[1] = f2bf(v.y);
        o.u[2] = f2bf(v.z); o.u[3] = f2bf(v.w);
        ((uint2*)xb)[i] = o.q;
    }
}

// ---- prep: weights -> staged layout ----
// wt_in[c9][kb4][fh2][n4][fi32][8i], wt_rk[g4][c18][kb4][fh2][n4][fi32][8i]
// co = n*64 + fh*32 + fi ; k = kb*8 + i (X: ci; H: (cc&1)*32 + kb*8+i)
__global__ __launch_bounds__(256)
void prep_w(const float* __restrict__ kern, const float* __restrict__ rk,
            u16* __restrict__ wt_in, u16* __restrict__ wt_rk) {
    int idx = blockIdx.x * 256 + threadIdx.x;
    if (idx >= 82944) return;
    const float* s;
    u16* dst;
    if (idx < 9216) {
        int fi = idx & 31, r1 = idx >> 5;
        int n = r1 & 3, r2 = r1 >> 2;
        int fh = r2 & 1, r3 = r2 >> 1;
        int kb = r3 & 3, tap = r3 >> 2;          // 0..8
        int co = (n << 6) + (fh << 5) + fi;
        s = kern + (size_t)((tap << 5) + (kb << 3)) * 256 + co;
        dst = wt_in + (size_t)idx * 8;
    } else {
        int j = idx - 9216;
        int fi = j & 31, r1 = j >> 5;
        int n = r1 & 3, r2 = r1 >> 2;
        int fh = r2 & 1, r3 = r2 >> 1;
        int kb = r3 & 3, r4 = r3 >> 2;           // 0..71 = g*18+cc
        int g = r4 / 18, cc = r4 - g * 18;
        int tap = cc >> 1;
        int cib = (cc & 1) << 5;
        int co = (n << 6) + (fh << 5) + fi;
        s = rk + (size_t)(((g * 9 + tap) << 6) + cib + (kb << 3)) * 256 + co;
        dst = wt_rk + (size_t)j * 8;
    }
    union { u16 u[8]; uint4 q; } o;
    #pragma unroll
    for (int i = 0; i < 8; ++i) o.u[i] = f2bf(s[i * 256]);
    *(uint4*)dst = o.q;
}

#define AS1U(p) ((const __attribute__((address_space(1))) u32*)(p))
#define AS3U(p) ((__attribute__((address_space(3))) u32*)(p))

// ---- fused conv + gates, one timestep ----
__global__ __launch_bounds__(512, 4)
void lstm_step(const u16* __restrict__ xb, const u16* __restrict__ wt_in,
               const u16* __restrict__ wt_rk, const float* __restrict__ bias,
               const int* __restrict__ labels, const u16* __restrict__ hrd,
               u16* __restrict__ hwr, float* __restrict__ cst,
               float* __restrict__ out, int t)
{
    // halo: X [kb4][180 pos][8] @0, H [kb8][180][8] @5760 ; wbuf 3x4096 @17280
    __shared__ short hal[17280 + 12288];   // 59,136 B -> 2 blocks/CU

    const int tid  = threadIdx.x;
    const int lane = tid & 63;
    const int w    = tid >> 6;
    const int pxq  = w >> 1;                  // 0..3 : 32-px group
    const int wq   = w & 1;                   // 0..1 : 16-f slice within fh
    const int bid  = blockIdx.x;
    const int fh   = bid & 1;
    const int tile = (bid >> 1) & 31;
    const int b    = bid >> 6;
    const int y0 = (tile >> 3) << 4, x0 = (tile & 7) << 3;
    const int g = labels[b];

    const int co_l = lane & 15;
    const int kbl  = lane >> 4;
    const int prow = (lane & 15) >> 3, pcol = lane & 7;
    const int fi = (wq << 4) + co_l;          // 0..31
    const int f  = (fh << 5) + fi;            // 0..63

    float bv[4];
    #pragma unroll
    for (int n = 0; n < 4; ++n)
        bv[n] = bias[(g << 8) + (n << 6) + f];

    int aoffm[2];
    #pragma unroll
    for (int mf = 0; mf < 2; ++mf)
        aoffm[mf] = ((pxq << 2) + (mf << 1) + prow) * 10 + pcol;

    // ---- c prefetch (latency hidden under chunks) + output offsets ----
    float* cb  = cst + ((size_t)b << 18);
    int coff[2][4];
    float cpre[2][4];
    #pragma unroll
    for (int mf = 0; mf < 2; ++mf)
        #pragma unroll
        for (int rr = 0; rr < 4; ++rr) {
            int p  = (pxq << 5) + (mf << 4) + (kbl << 2) + rr;
            int yy = y0 + (p >> 3), xx = x0 + (p & 7);
            coff[mf][rr] = (((yy << 6) + xx) << 6) + f;
            cpre[mf][rr] = (t > 0) ? cb[coff[mf][rr]] : 0.0f;
        }

    // ---- stage X halo (bf16), 720 slots ----
    {
        const u16* src = xb + ((size_t)(b * 10 + t) << 17);
        #pragma unroll 2
        for (int s = tid; s < 720; s += 512) {
            int pos = s >> 2, kb = s & 3;
            int hy = pos / 10, hx = pos - hy * 10;
            int gy = y0 + hy - 1, gx = x0 + hx - 1;
            short8v v = (short8v){0,0,0,0,0,0,0,0};
            if ((unsigned)gy < 64u && (unsigned)gx < 64u)
                v = *(const short8v*)&src[(((gy << 6) + gx) << 5) + (kb << 3)];
            *(short8v*)&hal[kb * 1440 + pos * 8] = v;
        }
    }
    // ---- stage H halo (bf16), 1440 slots ----
    if (t > 0) {
        const u16* src = hrd + ((size_t)b << 18);
        #pragma unroll 3
        for (int s = tid; s < 1440; s += 512) {
            int pos = s >> 3, kb = s & 7;
            int hy = pos / 10, hx = pos - hy * 10;
            int gy = y0 + hy - 1, gx = x0 + hx - 1;
            short8v v = (short8v){0,0,0,0,0,0,0,0};
            if ((unsigned)gy < 64u && (unsigned)gx < 64u)
                v = *(const short8v*)&src[(((gy << 6) + gx) << 6) + (kb << 3)];
            *(short8v*)&hal[5760 + kb * 1440 + pos * 8] = v;
        }
    }

    // weight stage: thread tid stages 16B of the 8KB chunk slab
    const int skb  = tid >> 7;                // kb of my 16B unit
    const int srem = tid & 127;               // unit within kb-piece
    auto issue_stage = [&](int c, int buf) {
        const u16* gsrc;
        if (c < 9)
            gsrc = wt_in + (size_t)((((c << 2) + skb) << 1) + fh) * 1024 + (srem << 3);
        else
            gsrc = wt_rk + (size_t)(((((g * 18 + (c - 9)) << 2) + skb) << 1) + fh) * 1024 + (srem << 3);
        __builtin_amdgcn_global_load_lds(AS1U(gsrc),
                                         AS3U(&hal[17280 + buf * 4096 + tid * 8]),
                                         16, 0, 0);
    };

    f32x4 acc[2][4];
    #pragma unroll
    for (int n = 0; n < 4; ++n)
        #pragma unroll
        for (int mf = 0; mf < 2; ++mf)
            acc[mf][n] = (f32x4){bv[n], bv[n], bv[n], bv[n]};

    const int nck = t ? 27 : 9;

    issue_stage(0, 0);
    __builtin_amdgcn_sched_barrier(0);
    asm volatile("s_waitcnt lgkmcnt(0)" ::: "memory");  // halo ds_writes done
    __builtin_amdgcn_sched_barrier(0);

    int bc = 0;                               // buffer holding chunk c
    #pragma unroll 1
    for (int c = 0; c < nck; ++c) {
        int bn = (bc == 2) ? 0 : bc + 1;      // buffer for chunk c+1
        if (c + 1 < nck) {
            issue_stage(c + 1, bn);
            __builtin_amdgcn_sched_barrier(0);
            asm volatile("s_waitcnt vmcnt(1)" ::: "memory");  // stage(c) landed
        } else {
            asm volatile("s_waitcnt vmcnt(0)" ::: "memory");
        }
        __builtin_amdgcn_sched_barrier(0);
        __builtin_amdgcn_s_barrier();         // all waves' stage(c) visible
        __builtin_amdgcn_sched_barrier(0);    // pin reads below barrier

        int koff, abase;
        if (c < 9) {
            koff = (c / 3) * 10 + (c % 3);
            abase = kbl * 1440;
        } else {
            int cc = c - 9, tap = cc >> 1;
            koff = (tap / 3) * 10 + (tap % 3);
            abase = 5760 + (((cc & 1) << 2) + kbl) * 1440;
        }
        const short* wb = &hal[17280 + bc * 4096 + kbl * 1024 + fi * 8];
        short8v bfr[4], af[2];
        #pragma unroll
        for (int n = 0; n < 4; ++n)
            bfr[n] = *(const short8v*)&wb[n * 256];
        #pragma unroll
        for (int mf = 0; mf < 2; ++mf)
            af[mf] = *(const short8v*)&hal[abase + (aoffm[mf] + koff) * 8];
        #pragma unroll
        for (int mf = 0; mf < 2; ++mf)
            #pragma unroll
            for (int n = 0; n < 4; ++n)
                acc[mf][n] = __builtin_amdgcn_mfma_f32_16x16x32_bf16(af[mf], bfr[n], acc[mf][n], 0, 0, 0);
        bc = bn;
    }

    // ---- gates in-register + writeback ----
    float* ob  = out + ((size_t)(b * 10 + t) << 18);
    u16*   hbw = hwr + ((size_t)b << 18);
    #pragma unroll
    for (int mf = 0; mf < 2; ++mf) {
        #pragma unroll
        for (int rr = 0; rr < 4; ++rr) {
            int off = coff[mf][rr];
            float zi = acc[mf][0][rr], zf = acc[mf][1][rr];
            float zg = acc[mf][2][rr], zo = acc[mf][3][rr];
            float cn = sigf(zf) * cpre[mf][rr] + sigf(zi) * tanhf_(zg);
            float hn = sigf(zo) * tanhf_(cn);
            cb[off]  = cn;
            ob[off]  = hn;
            hbw[off] = f2bf(hn);
        }
    }
}

extern "C" void kernel_launch(void* const* d_in, const int* in_sizes, int n_in,
                              void* d_out, int out_size, void* d_ws, size_t ws_size,
                              hipStream_t stream)
{
    const float* x    = (const float*)d_in[0];
    const int*   lbl  = (const int*)  d_in[1];
    const float* kern = (const float*)d_in[2];
    const float* rk   = (const float*)d_in[3];
    const float* bias = (const float*)d_in[4];
    float* out = (float*)d_out;

    // ws: xb 20.97MB | hb0 4.19 | hb1 4.19 | wt_in 0.147 | wt_rk 1.18 | c 8.39
    u16* xb    = (u16*)d_ws;
    u16* hb0   = xb + 10485760;
    u16* hb1   = hb0 + 2097152;
    u16* wt_in = hb1 + 2097152;
    u16* wt_rk = wt_in + 73728;
    float* cst = (float*)(wt_rk + 589824);

    hipLaunchKernelGGL(prep_x, dim3(2048), dim3(256), 0, stream, x, xb);
    hipLaunchKernelGGL(prep_w, dim3(324), dim3(256), 0, stream, kern, rk, wt_in, wt_rk);

    for (int t = 0; t < 10; ++t) {
        const u16* hrd = (t & 1) ? hb0 : hb1;
        u16*       hwr = (t & 1) ? hb1 : hb0;
        hipLaunchKernelGGL(lstm_step, dim3(512), dim3(512), 0, stream,
                           xb, wt_in, wt_rk, bias, lbl, hrd, hwr, cst, out, t);
    }
}